// Round 1
// baseline (88.647 us; speedup 1.0000x reference)
//
#include <hip/hip_runtime.h>

#define MAX_ATOMS 4096
#define N_RBF 16
#define N_HIDDEN 32
#define BLOCK 512                     // 8 waves -> 8 atoms per block
#define WAVES_PER_BLOCK (BLOCK / 64)

__global__ __launch_bounds__(BLOCK)
void ag3sr_fused_kernel(const float* __restrict__ pos,   // [n,3]
                        const float* __restrict__ W1,    // [16,32]
                        const float* __restrict__ b1,    // [32]
                        const float* __restrict__ W2,    // [32]
                        const float* __restrict__ b2,    // [1]
                        float* __restrict__ out,         // [1]
                        int n)
{
    __shared__ float sx[MAX_ATOMS], sy[MAX_ATOMS], sz[MAX_ATOMS];
    __shared__ float sW1[N_RBF * N_HIDDEN];
    __shared__ float sb1[N_HIDDEN], sW2[N_HIDDEN];
    __shared__ float swsum[WAVES_PER_BLOCK];

    const int tid = threadIdx.x;

    // Stage positions SoA into LDS (conflict-free stride-1 reads later)
    for (int idx = tid; idx < n; idx += BLOCK) {
        sx[idx] = pos[idx * 3 + 0];
        sy[idx] = pos[idx * 3 + 1];
        sz[idx] = pos[idx * 3 + 2];
    }
    for (int idx = tid; idx < N_RBF * N_HIDDEN; idx += BLOCK) sW1[idx] = W1[idx];
    if (tid < N_HIDDEN) { sb1[tid] = b1[tid]; sW2[tid] = W2[tid]; }
    __syncthreads();

    const int wave = tid >> 6;
    const int lane = tid & 63;
    const int atom = blockIdx.x * WAVES_PER_BLOCK + wave;

    // Constants exactly as the reference derives them
    const float w  = 5.0f / (float)(N_RBF - 1);          // width
    const float a  = 1.0f / (2.0f * w * w);              // inv_2w2
    const float NC = -a * 1.44269504088896340736f;       // -a * log2(e)

    float feat[N_RBF];
    #pragma unroll
    for (int k = 0; k < N_RBF; ++k) feat[k] = 0.0f;

    float xi = 0.f, yi = 0.f, zi = 0.f;
    if (atom < n) { xi = sx[atom]; yi = sy[atom]; zi = sz[atom]; }

    const int n_iters = n >> 6;  // 64 lanes sweep all j
    for (int it = 0; it < n_iters; ++it) {
        const int j = (it << 6) + lane;
        float dx = sx[j] - xi;
        float dy = sy[j] - yi;
        float dz = sz[j] - zi;
        float d2 = dx * dx;
        d2 = fmaf(dy, dy, d2);
        d2 = fmaf(dz, dz, d2);
        if (d2 > 0.0f && d2 < 25.0f) {   // (d2>0) & (sqrt(d2)<5)
            float d = sqrtf(d2);
            #pragma unroll
            for (int k = 0; k < N_RBF; ++k) {
                float u = d - (float)k * w;
                feat[k] += exp2f(u * u * NC);   // exp(-a*u^2), native v_exp_f32
            }
        }
    }

    // Butterfly-reduce each feature across the 64-lane wave (all lanes get sum)
    #pragma unroll
    for (int k = 0; k < N_RBF; ++k) {
        float v = feat[k];
        #pragma unroll
        for (int off = 32; off > 0; off >>= 1) v += __shfl_xor(v, off, 64);
        feat[k] = v;
    }

    // MLP: lane j (0..31) computes hidden unit j, then e = sum_j h_j * W2[j]
    float e = 0.0f;
    if (lane < N_HIDDEN) {
        float acc = sb1[lane];
        #pragma unroll
        for (int k = 0; k < N_RBF; ++k)
            acc = fmaf(feat[k], sW1[k * N_HIDDEN + lane], acc);
        // silu(acc) = acc * sigmoid(acc)
        float s = 1.0f / (1.0f + exp2f(-acc * 1.44269504088896340736f));
        e = acc * s * sW2[lane];
    }
    #pragma unroll
    for (int off = 32; off > 0; off >>= 1) e += __shfl_xor(e, off, 64);

    if (lane == 0) swsum[wave] = (atom < n) ? (e + b2[0]) : 0.0f;
    __syncthreads();
    if (tid == 0) {
        float bs = 0.0f;
        #pragma unroll
        for (int wv = 0; wv < WAVES_PER_BLOCK; ++wv) bs += swsum[wv];
        atomicAdd(out, bs);
    }
}

extern "C" void kernel_launch(void* const* d_in, const int* in_sizes, int n_in,
                              void* d_out, int out_size, void* d_ws, size_t ws_size,
                              hipStream_t stream) {
    const float* pos = (const float*)d_in[0];
    const float* W1  = (const float*)d_in[1];
    const float* b1  = (const float*)d_in[2];
    const float* W2  = (const float*)d_in[3];
    const float* b2  = (const float*)d_in[4];
    float* out = (float*)d_out;

    const int n = in_sizes[0] / 3;

    hipMemsetAsync(out, 0, sizeof(float), stream);

    const int grid = (n + WAVES_PER_BLOCK - 1) / WAVES_PER_BLOCK;
    ag3sr_fused_kernel<<<grid, BLOCK, 0, stream>>>(pos, W1, b1, W2, b2, out, n);
}

// Round 2
// 46.610 us; speedup vs baseline: 1.9019x; 1.9019x over previous
//
#include <hip/hip_runtime.h>

#define MAX_ATOMS 4096
#define N_RBF 16
#define N_HIDDEN 32
#define BLOCK 512                     // 8 waves -> 8 atoms per block
#define WAVES_PER_BLOCK (BLOCK / 64)

__global__ __launch_bounds__(BLOCK)
void ag3sr_fused_kernel(const float* __restrict__ pos,   // [n,3]
                        const float* __restrict__ W1,    // [16,32]
                        const float* __restrict__ b1,    // [32]
                        const float* __restrict__ W2,    // [32]
                        const float* __restrict__ b2,    // [1]
                        float* __restrict__ out,         // [1]
                        int n)
{
    __shared__ float sx[MAX_ATOMS], sy[MAX_ATOMS], sz[MAX_ATOMS];
    __shared__ float sW1[N_RBF * N_HIDDEN];
    __shared__ float sb1[N_HIDDEN], sW2[N_HIDDEN];
    __shared__ float swsum[WAVES_PER_BLOCK];

    const int tid = threadIdx.x;

    // Stage positions SoA into LDS (stride-1 lane access = conflict-free)
    for (int idx = tid; idx < n; idx += BLOCK) {
        sx[idx] = pos[idx * 3 + 0];
        sy[idx] = pos[idx * 3 + 1];
        sz[idx] = pos[idx * 3 + 2];
    }
    for (int idx = tid; idx < N_RBF * N_HIDDEN; idx += BLOCK) sW1[idx] = W1[idx];
    if (tid < N_HIDDEN) { sb1[tid] = b1[tid]; sW2[tid] = W2[tid]; }
    __syncthreads();

    const int wave = tid >> 6;
    const int lane = tid & 63;
    const int atom = blockIdx.x * WAVES_PER_BLOCK + wave;

    // Gaussian-grid recurrence constants (a = 4.5, w = 1/3):
    //   r_k = exp(-a (d - k w)^2);  r_{k+1} = r_k * s_k;  s_{k+1} = s_k * e^-1
    //   r_0 = exp(-a d^2),  s_0 = exp(3 d - 0.5)
    // Chain run scaled by 2^80 so r_0 never underflows for d < 5.
    const float LOG2E = 1.44269504088896340736f;
    const float NC    = -4.5f * LOG2E;            // exp2 coeff for r_0
    const float S0A   = 3.0f * LOG2E;             // exp2 coeffs for s_0
    const float S0B   = -0.5f * LOG2E;
    const float EINV  = 0.36787944117144233f;     // e^-1
    const float BIAS  = 80.0f;                    // scale = 2^80
    const float UNSC  = 8.271806125530277e-25f;   // 2^-80 (exact)

    float feat[N_RBF];
    #pragma unroll
    for (int k = 0; k < N_RBF; ++k) feat[k] = 0.0f;

    float xi = 0.f, yi = 0.f, zi = 0.f;
    if (atom < n) { xi = sx[atom]; yi = sy[atom]; zi = sz[atom]; }

    const int n_iters = n >> 6;  // 64 lanes sweep all j (n % 64 == 0)
    #pragma unroll 2
    for (int it = 0; it < n_iters; ++it) {
        const int j = (it << 6) + lane;
        float dx = sx[j] - xi;
        float dy = sy[j] - yi;
        float dz = sz[j] - zi;
        float d2 = dx * dx;
        d2 = fmaf(dy, dy, d2);
        d2 = fmaf(dz, dz, d2);
        float d = __builtin_amdgcn_sqrtf(d2);                    // raw v_sqrt_f32
        float r = __builtin_amdgcn_exp2f(fmaf(d2, NC, BIAS));    // 2^80 * exp(-a d^2)
        float s = __builtin_amdgcn_exp2f(fmaf(d, S0A, S0B));     // exp(3d - 0.5)
        // mask (d2>0) & (d<5); r==0 propagates through the whole chain
        r = ((d2 > 0.0f) & (d2 < 25.0f)) ? r : 0.0f;
        #pragma unroll
        for (int k = 0; k < N_RBF; ++k) {
            feat[k] += r;
            r *= s;
            s *= EINV;
        }
    }

    // Butterfly-reduce each feature across the 64-lane wave, unscale
    #pragma unroll
    for (int k = 0; k < N_RBF; ++k) {
        float v = feat[k];
        #pragma unroll
        for (int off = 32; off > 0; off >>= 1) v += __shfl_xor(v, off, 64);
        feat[k] = v * UNSC;
    }

    // MLP: lane j (0..31) computes hidden unit j, then e = sum_j h_j * W2[j]
    float e = 0.0f;
    if (lane < N_HIDDEN) {
        float acc = sb1[lane];
        #pragma unroll
        for (int k = 0; k < N_RBF; ++k)
            acc = fmaf(feat[k], sW1[k * N_HIDDEN + lane], acc);
        float s = 1.0f / (1.0f + __builtin_amdgcn_exp2f(-acc * LOG2E));
        e = acc * s * sW2[lane];
    }
    #pragma unroll
    for (int off = 32; off > 0; off >>= 1) e += __shfl_xor(e, off, 64);

    if (lane == 0) swsum[wave] = (atom < n) ? (e + b2[0]) : 0.0f;
    __syncthreads();
    if (tid == 0) {
        float bs = 0.0f;
        #pragma unroll
        for (int wv = 0; wv < WAVES_PER_BLOCK; ++wv) bs += swsum[wv];
        atomicAdd(out, bs);
    }
}

extern "C" void kernel_launch(void* const* d_in, const int* in_sizes, int n_in,
                              void* d_out, int out_size, void* d_ws, size_t ws_size,
                              hipStream_t stream) {
    const float* pos = (const float*)d_in[0];
    const float* W1  = (const float*)d_in[1];
    const float* b1  = (const float*)d_in[2];
    const float* W2  = (const float*)d_in[3];
    const float* b2  = (const float*)d_in[4];
    float* out = (float*)d_out;

    const int n = in_sizes[0] / 3;

    hipMemsetAsync(out, 0, sizeof(float), stream);

    const int grid = (n + WAVES_PER_BLOCK - 1) / WAVES_PER_BLOCK;
    ag3sr_fused_kernel<<<grid, BLOCK, 0, stream>>>(pos, W1, b1, W2, b2, out, n);
}

// Round 3
// 37.651 us; speedup vs baseline: 2.3544x; 1.2380x over previous
//
#include <hip/hip_runtime.h>

#define N_RBF 16
#define N_HIDDEN 32
#define BLOCK 256                       // 4 waves
#define WAVES_PER_BLOCK (BLOCK / 64)
#define TILE 2048                       // position tile staged in LDS
#define QCAP 128                        // per-wave d2 ring buffer (power of 2)

// Gaussian-grid recurrence constants (a = 4.5, w = 1/3):
//   r_k = exp(-a (d - k w)^2) ; r_0 = exp(-a d^2) ; s_k = exp(3d - 0.5 - k)
//   r_{k+1} = r_k * s_k.  Even/odd split: r_{k+2} = r_k * u_k, u_k = s^2 e^{-(2k+1)}
// Chain scaled by 2^80 so r_0 never underflows for d < 5.
#define LOG2E 1.44269504088896340736f
#define NC   (-4.5f * LOG2E)
#define S0A  (3.0f * LOG2E)
#define S0B  (-0.5f * LOG2E)
#define BIAS 80.0f
#define UNSC 8.271806125530277e-25f     // 2^-80
#define C_E1 0.36787944117144233f       // e^-1
#define C_E3 0.049787068367863944f      // e^-3
#define C_E4 0.018315638888734179f      // e^-4

__device__ __forceinline__ void rbf_batch(float d2, bool active, float feat[N_RBF]) {
    float d  = __builtin_amdgcn_sqrtf(d2);
    float r0 = __builtin_amdgcn_exp2f(fmaf(d2, NC, BIAS));   // 2^80 * exp(-a d^2)
    float s  = __builtin_amdgcn_exp2f(fmaf(d, S0A, S0B));    // exp(3d - 0.5)
    float r1 = r0 * s;
    if (!active) { r0 = 0.0f; r1 = 0.0f; }
    float s2 = s * s;
    float ue = s2 * C_E1;
    float uo = s2 * C_E3;
    #pragma unroll
    for (int k = 0; k < N_RBF; k += 2) {
        feat[k]     += r0;
        feat[k + 1] += r1;
        r0 *= ue;  r1 *= uo;
        ue *= C_E4; uo *= C_E4;
    }
}

__global__ __launch_bounds__(BLOCK)
void ag3sr_fused_kernel(const float* __restrict__ pos,   // [n,3]
                        const float* __restrict__ W1,    // [16,32]
                        const float* __restrict__ b1,    // [32]
                        const float* __restrict__ W2,    // [32]
                        const float* __restrict__ b2,    // [1]
                        float* __restrict__ out,         // [1]
                        int n)
{
    __shared__ float sx[TILE], sy[TILE], sz[TILE];
    __shared__ float sq[WAVES_PER_BLOCK][QCAP];
    __shared__ float sW1[N_RBF * N_HIDDEN];
    __shared__ float sb1[N_HIDDEN], sW2[N_HIDDEN];
    __shared__ float swsum[WAVES_PER_BLOCK];

    const int tid  = threadIdx.x;
    const int wave = tid >> 6;
    const int lane = tid & 63;
    const int atom = blockIdx.x * WAVES_PER_BLOCK + wave;

    for (int idx = tid; idx < N_RBF * N_HIDDEN; idx += BLOCK) sW1[idx] = W1[idx];
    if (tid < N_HIDDEN) { sb1[tid] = b1[tid]; sW2[tid] = W2[tid]; }

    float xi = 0.f, yi = 0.f, zi = 0.f;
    if (atom < n) {
        xi = pos[atom * 3 + 0];
        yi = pos[atom * 3 + 1];
        zi = pos[atom * 3 + 2];
    }

    float feat[N_RBF];
    #pragma unroll
    for (int k = 0; k < N_RBF; ++k) feat[k] = 0.0f;

    int count = 0, processed = 0;

    for (int t0 = 0; t0 < n; t0 += TILE) {
        __syncthreads();   // all waves done reading previous tile
        for (int idx = tid; idx < TILE; idx += BLOCK) {
            int g = t0 + idx;
            if (g < n) {
                sx[idx] = pos[g * 3 + 0];
                sy[idx] = pos[g * 3 + 1];
                sz[idx] = pos[g * 3 + 2];
            } else {
                sx[idx] = 1e9f; sy[idx] = 1e9f; sz[idx] = 1e9f;
            }
        }
        __syncthreads();

        for (int it = 0; it < TILE / 64; ++it) {
            const int j = (it << 6) + lane;
            float dx = sx[j] - xi;
            float dy = sy[j] - yi;
            float dz = sz[j] - zi;
            float d2 = dx * dx;
            d2 = fmaf(dy, dy, d2);
            d2 = fmaf(dz, dz, d2);
            bool pass = (d2 > 0.0f) & (d2 < 25.0f);

            unsigned long long m = __ballot(pass);
            unsigned lo = (unsigned)m, hi = (unsigned)(m >> 32);
            int prefix = __builtin_amdgcn_mbcnt_hi(hi, __builtin_amdgcn_mbcnt_lo(lo, 0u));
            if (pass) sq[wave][(count + prefix) & (QCAP - 1)] = d2;
            count += __popcll(m);

            if (count - processed >= 64) {   // wave-uniform drain
                float qd2 = sq[wave][(processed + lane) & (QCAP - 1)];
                processed += 64;
                rbf_batch(qd2, true, feat);
            }
        }
    }

    // tail drain (rem in [0,63])
    {
        int rem = count - processed;
        if (rem > 0) {
            bool active = lane < rem;
            float qd2 = active ? sq[wave][(processed + lane) & (QCAP - 1)] : 0.0f;
            rbf_batch(qd2, active, feat);
        }
    }

    // Butterfly-reduce features across the wave, unscale the 2^80 bias
    #pragma unroll
    for (int k = 0; k < N_RBF; ++k) {
        float v = feat[k];
        #pragma unroll
        for (int off = 32; off > 0; off >>= 1) v += __shfl_xor(v, off, 64);
        feat[k] = v * UNSC;
    }

    // MLP: lane j (0..31) computes hidden unit j, e = sum_j silu(h_j) * W2[j]
    float e = 0.0f;
    if (lane < N_HIDDEN) {
        float acc = sb1[lane];
        #pragma unroll
        for (int k = 0; k < N_RBF; ++k)
            acc = fmaf(feat[k], sW1[k * N_HIDDEN + lane], acc);
        float sg = 1.0f / (1.0f + __builtin_amdgcn_exp2f(-acc * LOG2E));
        e = acc * sg * sW2[lane];
    }
    #pragma unroll
    for (int off = 32; off > 0; off >>= 1) e += __shfl_xor(e, off, 64);

    if (lane == 0) swsum[wave] = (atom < n) ? (e + b2[0]) : 0.0f;
    __syncthreads();
    if (tid == 0) {
        float bs = 0.0f;
        #pragma unroll
        for (int wv = 0; wv < WAVES_PER_BLOCK; ++wv) bs += swsum[wv];
        atomicAdd(out, bs);
    }
}

extern "C" void kernel_launch(void* const* d_in, const int* in_sizes, int n_in,
                              void* d_out, int out_size, void* d_ws, size_t ws_size,
                              hipStream_t stream) {
    const float* pos = (const float*)d_in[0];
    const float* W1  = (const float*)d_in[1];
    const float* b1  = (const float*)d_in[2];
    const float* W2  = (const float*)d_in[3];
    const float* b2  = (const float*)d_in[4];
    float* out = (float*)d_out;

    const int n = in_sizes[0] / 3;

    hipMemsetAsync(out, 0, sizeof(float), stream);

    const int grid = (n + WAVES_PER_BLOCK - 1) / WAVES_PER_BLOCK;
    ag3sr_fused_kernel<<<grid, BLOCK, 0, stream>>>(pos, W1, b1, W2, b2, out, n);
}